// Round 4
// baseline (295.980 us; speedup 1.0000x reference)
//
#include <hip/hip_runtime.h>

#define NUM_USERS 50000
#define NUM_ITEMS 50000
#define N_NODES   100000
#define NNZ       3200000
#define EMB_DIM   64
#define N_LAYERS  3
#define BATCH     16384

#define NBUCK 512
#define ABITS 8                  // bucket = dst >> 8 (256 nodes/bucket, 391 used)
#define NODES_PER_BUCK 256
#define TILE_EDGES 8192
#define NBUCK_USED ((N_NODES + NODES_PER_BUCK - 1) / NODES_PER_BUCK)   // 391
#define CAP 9472                 // padded capacity (mean 8192 + node pads ~384 + >10 sigma slack)
#define NCELL 1024               // 256 nodes x 4 src-quarters (quarter-SORT only, no quarter pads)

typedef unsigned long long ull;
typedef float v2f __attribute__((ext_vector_type(2)));

// ---- bf16 helpers (RNE) ----
__device__ inline unsigned bf16pair(float a, float b) {
    unsigned ua = __float_as_uint(a), ub = __float_as_uint(b);
    unsigned r0 = (ua + 0x7fffu + ((ua >> 16) & 1u)) >> 16;
    unsigned r1 = (ub + 0x7fffu + ((ub >> 16) & 1u)) >> 16;
    return r0 | (r1 << 16);
}
__device__ inline float blo(unsigned u) { return __uint_as_float(u << 16); }
__device__ inline float bhi(unsigned u) { return __uint_as_float(u & 0xffff0000u); }

// packed 2xf32 ops (VOP3P; halves independent)
__device__ inline void pkfma(v2f& d, v2f a, v2f b) {
    asm("v_pk_fma_f32 %0, %1, %2, %0" : "+v"(d) : "v"(a), "v"(b));
}

// accumulate one edge's 8 bf16 dims (uint4) with UNscaled integer weight (r>>17).
// 2^-15 scale folded into epilogue (exact power of 2 -> bit-identical weights).
// Zero record (pad) -> w=0, harmless.
__device__ inline void accP(v2f& sA, v2f& sB, v2f& sC, v2f& sD, uint4 g, unsigned r) {
    float w = (float)(r >> 17);
    v2f w2 = {w, w};
    v2f e0 = {blo(g.x), bhi(g.x)};
    v2f e1 = {blo(g.y), bhi(g.y)};
    v2f e2 = {blo(g.z), bhi(g.z)};
    v2f e3 = {blo(g.w), bhi(g.w)};
    pkfma(sA, e0, w2);
    pkfma(sB, e1, w2);
    pkfma(sC, e2, w2);
    pkfma(sD, e3, w2);
}

// gather one uint4 (8 bf16 dims) of node src at dim-octet byte offset dOff.
__device__ inline uint4 gath(const unsigned char* __restrict__ base, unsigned r, unsigned dOff) {
    unsigned off = ((r & 0x1FFFFu) << 7) + dOff;
    return *(const uint4*)(base + off);
}

// one 4-edge round: plain 16B record load (node runs are padded to 4 with ZERO
// records, so no predication needed) + 4 gathers + 4 packed-FMA accumulates.
__device__ inline void roundU(const unsigned char* __restrict__ A16,
                              const unsigned* __restrict__ p, unsigned dOff,
                              v2f& sA, v2f& sB, v2f& sC, v2f& sD) {
    uint4 R = *(const uint4*)p;
    uint4 g0 = gath(A16, R.x, dOff);
    uint4 g1 = gath(A16, R.y, dOff);
    uint4 g2 = gath(A16, R.z, dOff);
    uint4 g3 = gath(A16, R.w, dOff);
    accP(sA, sB, sC, sD, g0, R.x);
    accP(sA, sB, sC, sD, g1, R.y);
    accP(sA, sB, sC, sD, g2, R.z);
    accP(sA, sB, sC, sD, g3, R.w);
}

// ---- shared pull body: one eg (8 lanes) owns TWO node streams end-to-end.
// Records are src-quarter-sorted per node -> all concurrently-running egs walk
// the src table low->high in position lockstep (soft L2 window), with zero
// padding overhead. deg[] is the padded run length (multiple of 4, pads zeroed).
__device__ inline void pull_pair(const unsigned char* __restrict__ A16,
                                 uint4* __restrict__ B16,
                                 const unsigned* __restrict__ sorted,
                                 const int* __restrict__ rowStart,
                                 const int* __restrict__ deg,
                                 int nA, int nB, int d8, unsigned dOff) {
    int dA = deg[nA], dB = deg[nB];
    const unsigned* pA = sorted + rowStart[nA];
    const unsigned* pB = sorted + rowStart[nB];

    v2f s00 = {0.f,0.f}, s01 = {0.f,0.f}, s02 = {0.f,0.f}, s03 = {0.f,0.f};
    v2f s10 = {0.f,0.f}, s11 = {0.f,0.f}, s12 = {0.f,0.f}, s13 = {0.f,0.f};

    // 12 conditional rounds cover deg<=48 (P(Poisson(32)>48) ~ 0.25%/node).
    // Per-eg divergent conditions: masked egs issue ZERO memory requests.
    #pragma unroll
    for (int base = 0; base < 48; base += 4) {
        if (dA > base) roundU(A16, pA + base, dOff, s00, s01, s02, s03);
        if (dB > base) roundU(A16, pB + base, dOff, s10, s11, s12, s13);
    }
    if (__builtin_expect((dA > 48) || (dB > 48), 0)) {
        for (int base = 48; base < dA; base += 4)
            roundU(A16, pA + base, dOff, s00, s01, s02, s03);
        for (int base = 48; base < dB; base += 4)
            roundU(A16, pB + base, dOff, s10, s11, s12, s13);
    }

    const float k15 = 1.f / 32768.f;   // fold fix15 weight scale (exact pow2)
    uint4 h;
    h.x = bf16pair(s00.x * k15, s00.y * k15);
    h.y = bf16pair(s01.x * k15, s01.y * k15);
    h.z = bf16pair(s02.x * k15, s02.y * k15);
    h.w = bf16pair(s03.x * k15, s03.y * k15);
    B16[(((long long)nA) << 3) + d8] = h;
    h.x = bf16pair(s10.x * k15, s10.y * k15);
    h.y = bf16pair(s11.x * k15, s11.y * k15);
    h.z = bf16pair(s12.x * k15, s12.y * k15);
    h.w = bf16pair(s13.x * k15, s13.y * k15);
    B16[(((long long)nB) << 3) + d8] = h;
}

// init: E0(bf16) = concat(ue, ie). Block 0 inits bucket cursors.
__global__ void init_emb_kernel(const float* __restrict__ ue,
                                const float* __restrict__ ie,
                                unsigned* __restrict__ E0,
                                int* __restrict__ bucketCursor) {
    int idx = blockIdx.x * blockDim.x + threadIdx.x;   // per float4 (4 dims)
    if (blockIdx.x == 0 && threadIdx.x < 256) {
        bucketCursor[threadIdx.x]       = threadIdx.x * CAP;
        bucketCursor[threadIdx.x + 256] = (threadIdx.x + 256) * CAP;
    }
    const int total = N_NODES * (EMB_DIM / 4);
    if (idx >= total) return;
    const int uoff = NUM_USERS * (EMB_DIM / 4);
    float4 v;
    if (idx < uoff) v = ((const float4*)ue)[idx];
    else            v = ((const float4*)ie)[idx - uoff];
    uint2 h;
    h.x = bf16pair(v.x, v.y);
    h.y = bf16pair(v.z, v.w);
    ((uint2*)E0)[idx] = h;
}

// partition edges into padded dst-bucket regions. 1024 threads, 8 edges/thread.
// rec: src(17) | dstLocal(8)<<17 | fix15(val)<<25
__global__ void partA_kernel(const float* __restrict__ ev,
                             const int*  __restrict__ es,
                             const int*  __restrict__ ed,
                             int* __restrict__ bucketCursor,
                             ull* __restrict__ tmp) {
    __shared__ int hist[NBUCK];
    __shared__ int base[NBUCK];
    __shared__ int cnt2[NBUCK];
    int tid = threadIdx.x;            // 1024
    int e0 = blockIdx.x * TILE_EDGES;

    int      mySrc[8], myDst[8];
    unsigned myQ[8];

    for (int i = tid; i < NBUCK; i += 1024) hist[i] = 0;
    __syncthreads();

    #pragma unroll
    for (int k = 0; k < 8; ++k) {
        int e = e0 + k * 1024 + tid;
        if (e < NNZ) {
            mySrc[k] = es[e];
            myDst[k] = ed[e];
            myQ[k]   = (unsigned)fminf(ev[e] * 32768.f + 0.5f, 32767.f);
            atomicAdd(&hist[((unsigned)myDst[k]) >> ABITS], 1);
        } else {
            myDst[k] = -1;
        }
    }
    __syncthreads();

    for (int i = tid; i < NBUCK; i += 1024) {
        int c = hist[i];
        base[i] = c ? atomicAdd(&bucketCursor[i], c) : 0;
        cnt2[i] = 0;
    }
    __syncthreads();

    #pragma unroll
    for (int k = 0; k < 8; ++k) {
        int dst = myDst[k];
        if (dst < 0) continue;
        int b = ((unsigned)dst) >> ABITS;
        int pos = base[b] + atomicAdd(&cnt2[b], 1);
        if (pos < (b + 1) * CAP) {   // statistically unreachable overflow guard
            ull rec = (ull)(unsigned)(mySrc[k] | ((dst & (NODES_PER_BUCK - 1)) << 17))
                    | ((ull)myQ[k] << 25);
            tmp[pos] = rec;
        }
    }
}

// partB: per bucket — 1024-cell (node x src-quarter) histogram gives each node a
// contiguous, src-quarter-SORTED record run, padded only to a multiple of 4 with
// ZEROED pad records. deg[node] = padded run length. Node-level scan (256 elems).
// sorted rec (u32): src(17)|fix15<<17
__global__ void partB_kernel(const ull* __restrict__ tmp,
                             const int* __restrict__ bucketCursor,
                             int* __restrict__ rowStart,
                             int* __restrict__ deg,
                             unsigned* __restrict__ sorted) {
    __shared__ int cnt[NCELL];
    __shared__ int nsc[NODES_PER_BUCK];     // scan of pad4(node total)
    __shared__ int nstart[NODES_PER_BUCK];
    __shared__ int cur[NCELL];
    int b = blockIdx.x;
    int tid = threadIdx.x;           // 1024
    int nodeLo = b << ABITS;
    int startE = b * CAP;
    int endE   = bucketCursor[b];    // base + records in bucket

    cnt[tid] = 0;
    __syncthreads();

    ull myRec[9];
    int myCell[9];
    int nRec = 0;
    #pragma unroll
    for (int k = 0; k < 9; ++k) {
        int i = startE + k * 1024 + tid;
        if (i < endE) {
            myRec[k] = tmp[i];
            nRec = k + 1;
            unsigned src = (unsigned)(myRec[k] & 0x1FFFFULL);
            int q = (int)(src >> 15); if (q > 3) q = 3;
            int dl = (int)((myRec[k] >> 17) & (NODES_PER_BUCK - 1));
            myCell[k] = (dl << 2) + q;
            atomicAdd(&cnt[myCell[k]], 1);
        }
    }
    __syncthreads();

    int p4 = 0;
    if (tid < NODES_PER_BUCK) {
        int tot = cnt[tid*4] + cnt[tid*4+1] + cnt[tid*4+2] + cnt[tid*4+3];
        p4 = (tot + 3) & ~3;
        nsc[tid] = p4;
    }
    __syncthreads();
    for (int o = 1; o < NODES_PER_BUCK; o <<= 1) {
        int add = 0;
        if (tid < NODES_PER_BUCK && tid >= o) add = nsc[tid - o];
        __syncthreads();
        if (tid < NODES_PER_BUCK) nsc[tid] += add;
        __syncthreads();
    }
    if (tid < NODES_PER_BUCK) {
        int ns = startE + nsc[tid] - p4;   // 16B-aligned (startE%4==0, scan of x4)
        nstart[tid] = ns;
        int node = nodeLo + tid;
        if (node < N_NODES) {
            rowStart[node] = ns;
            deg[node] = p4;                // PADDED length; pads zeroed below
        }
    }
    __syncthreads();

    {   // exact (unpadded) cell cursors within each node's run
        int n = tid >> 2, q = tid & 3;
        int c = nstart[n];
        if (q > 0) c += cnt[n*4];
        if (q > 1) c += cnt[n*4+1];
        if (q > 2) c += cnt[n*4+2];
        cur[tid] = c;
    }
    __syncthreads();

    for (int k = 0; k < nRec; ++k) {
        ull rec = myRec[k];
        unsigned o = (unsigned)(rec & 0x1FFFFULL) | ((unsigned)((rec >> 25) & 0x7FFF) << 17);
        int pos = atomicAdd(&cur[myCell[k]], 1);
        if (pos < startE + CAP) sorted[pos] = o;  // overflow guard (stat. unreachable)
    }
    __syncthreads();

    if (tid < NODES_PER_BUCK) {        // zero the <=3 pad slots at each node tail
        int tot = cnt[tid*4] + cnt[tid*4+1] + cnt[tid*4+2] + cnt[tid*4+3];
        int end = nstart[tid] + ((tot + 3) & ~3);
        for (int p = nstart[tid] + tot; p < end; ++p)
            if (p < startE + CAP) sorted[p] = 0;
    }
}

// ---- pull_sync (ungated layers): wave covers 16 consecutive nodes, eg owns 2.
__global__ void __launch_bounds__(256, 6)
pull_sync_kernel(const unsigned char* __restrict__ A16,
                 uint4* __restrict__ B16,
                 const unsigned* __restrict__ sorted,
                 const int* __restrict__ rowStart,
                 const int* __restrict__ deg) {
    int wid = (blockIdx.x << 2) + (threadIdx.x >> 6);
    if (wid >= N_NODES / 16) return;          // 6250 waves x 16 nodes
    int lane = threadIdx.x & 63;
    int eg = lane >> 3;
    int d8 = lane & 7;
    unsigned dOff = (unsigned)d8 << 4;
    int nA = (wid << 4) + (eg << 1);          // nA, nA+1 <= 99999
    pull_pair(A16, B16, sorted, rowStart, deg, nA, nA + 1, d8, dOff);
}

// ---- pull_gated (layer 3): dense sweep of the 32768 user/item entries — no
// flags, no dead waves. Duplicate entries recompute and store byte-identical
// rows (benign race).
__global__ void __launch_bounds__(256, 6)
pull_gated_kernel(const unsigned char* __restrict__ A16,
                  uint4* __restrict__ B16,
                  const unsigned* __restrict__ sorted,
                  const int* __restrict__ rowStart,
                  const int* __restrict__ deg,
                  const int* __restrict__ users,
                  const int* __restrict__ items) {
    int wid = (blockIdx.x << 2) + (threadIdx.x >> 6);
    if (wid >= (2 * BATCH) / 16) return;      // 2048 waves x 16 entries
    int lane = threadIdx.x & 63;
    int eg = lane >> 3;
    int d8 = lane & 7;
    unsigned dOff = (unsigned)d8 << 4;
    int e = (wid << 4) + (eg << 1);           // even entry index
    int nA = (e     < BATCH) ? users[e]     : NUM_USERS + items[e - BATCH];
    int nB = (e + 1 < BATCH) ? users[e + 1] : NUM_USERS + items[e + 1 - BATCH];
    pull_pair(A16, B16, sorted, rowStart, deg, nA, nB, d8, dOff);
}

// dot: half-wave (32 lanes) per batch element; lane covers 2 dims (one uint).
// gamma = dot( sum_l U_l , sum_l I_l ) / 16, layers read from E0,B1,B2,B3.
__global__ void dot_kernel(const unsigned* __restrict__ E0,
                           const unsigned* __restrict__ B1,
                           const unsigned* __restrict__ B2,
                           const unsigned* __restrict__ B3,
                           const int* __restrict__ users,
                           const int* __restrict__ items,
                           float* __restrict__ out) {
    int t = blockIdx.x * blockDim.x + threadIdx.x;
    int b = t >> 5;
    int lane = t & 31;
    if (b >= BATCH) return;
    long long uo = ((long long)users[b] << 5) + lane;
    long long io = ((long long)(items[b] + NUM_USERS) << 5) + lane;
    unsigned a0 = E0[uo], a1 = B1[uo], a2 = B2[uo], a3 = B3[uo];
    unsigned c0 = E0[io], c1 = B1[io], c2 = B2[io], c3 = B3[io];
    float ux = (blo(a0) + blo(a1)) + (blo(a2) + blo(a3));
    float uy = (bhi(a0) + bhi(a1)) + (bhi(a2) + bhi(a3));
    float ix = (blo(c0) + blo(c1)) + (blo(c2) + blo(c3));
    float iy = (bhi(c0) + bhi(c1)) + (bhi(c2) + bhi(c3));
    float p = ux * ix + uy * iy;
    #pragma unroll
    for (int off = 16; off >= 1; off >>= 1)
        p += __shfl_xor(p, off, 64);   // stays within the aligned 32-group
    if (lane == 0) out[b] = p * 0.0625f;
}

extern "C" void kernel_launch(void* const* d_in, const int* in_sizes, int n_in,
                              void* d_out, int out_size, void* d_ws, size_t ws_size,
                              hipStream_t stream) {
    const float* user_emb = (const float*)d_in[0];
    const float* item_emb = (const float*)d_in[1];
    const float* edge_val = (const float*)d_in[2];
    const int*   edge_src = (const int*)d_in[3];
    const int*   edge_dst = (const int*)d_in[4];
    const int*   users    = (const int*)d_in[5];
    const int*   items    = (const int*)d_in[6];
    float* out = (float*)d_out;

    const size_t emb16Bytes = (size_t)N_NODES * EMB_DIM * 2;               // 12.8 MB
    const size_t sortBytes  = (size_t)NBUCK_USED * CAP * sizeof(unsigned); // 14.8 MB
    const size_t tmpBytes   = (size_t)NBUCK_USED * CAP * sizeof(ull);      // 29.6 MB
    const size_t nodeBytes  = (size_t)N_NODES * sizeof(int);               // 400 KB

    char* w = (char*)d_ws;
    unsigned* E0           = (unsigned*)(w); w += emb16Bytes;
    unsigned* B1           = (unsigned*)(w); w += emb16Bytes;
    unsigned* B2           = (unsigned*)(w); w += emb16Bytes;
    unsigned* B3           = (unsigned*)(w); w += emb16Bytes;
    unsigned* sorted       = (unsigned*)(w); w += sortBytes;
    ull*      tmp          = (ull*)(w);      w += tmpBytes;
    int*      deg          = (int*)(w);      w += nodeBytes;
    int*      rowStart     = (int*)(w);      w += nodeBytes;
    int*      bucketCursor = (int*)(w);      w += NBUCK * sizeof(int);

    const int vecTotal   = N_NODES * (EMB_DIM / 4);
    const int initBlocks = (vecTotal + 255) / 256;
    const int tileBlocks = (NNZ + TILE_EDGES - 1) / TILE_EDGES;   // 391

    init_emb_kernel<<<initBlocks, 256, 0, stream>>>(user_emb, item_emb, E0, bucketCursor);

    partA_kernel<<<tileBlocks, 1024, 0, stream>>>(edge_val, edge_src, edge_dst,
                                                  bucketCursor, tmp);
    partB_kernel<<<NBUCK_USED, 1024, 0, stream>>>(tmp, bucketCursor,
                                                  rowStart, deg, sorted);

    const int syncBlocks = (N_NODES / 16 + 3) / 4;                // 1563
    pull_sync_kernel<<<syncBlocks, 256, 0, stream>>>((const unsigned char*)E0, (uint4*)B1,
                                                     sorted, rowStart, deg);
    pull_sync_kernel<<<syncBlocks, 256, 0, stream>>>((const unsigned char*)B1, (uint4*)B2,
                                                     sorted, rowStart, deg);

    const int gatedBlocks = ((2 * BATCH) / 16 + 3) / 4;           // 512
    pull_gated_kernel<<<gatedBlocks, 256, 0, stream>>>((const unsigned char*)B2, (uint4*)B3,
                                                       sorted, rowStart, deg, users, items);

    const int dotBlocks = (BATCH * 32 + 255) / 256;
    dot_kernel<<<dotBlocks, 256, 0, stream>>>(E0, B1, B2, B3, users, items, out);
}

// Round 6
// 279.547 us; speedup vs baseline: 1.0588x; 1.0588x over previous
//
#include <hip/hip_runtime.h>

#define NUM_USERS 50000
#define NUM_ITEMS 50000
#define N_NODES   100000
#define NNZ       3200000
#define EMB_DIM   64
#define N_LAYERS  3
#define BATCH     16384

#define NBUCK 512
#define ABITS 8                  // bucket = dst >> 8 (256 nodes/bucket, 391 used)
#define NODES_PER_BUCK 256
#define TILE_EDGES 8192
#define NBUCK_USED ((N_NODES + NODES_PER_BUCK - 1) / NODES_PER_BUCK)   // 391
#define CAP 9472                 // padded capacity (mean 8192 + node pads ~384 + >10 sigma slack)
#define NCELL 1024               // 256 nodes x 4 src-quarters (quarter-SORT only, residual locality)

typedef unsigned long long ull;
typedef float v2f __attribute__((ext_vector_type(2)));
typedef unsigned v4u __attribute__((ext_vector_type(4)));   // native vec for nt builtins

// ---- bf16 helpers (RNE) ----
__device__ inline unsigned bf16pair(float a, float b) {
    unsigned ua = __float_as_uint(a), ub = __float_as_uint(b);
    unsigned r0 = (ua + 0x7fffu + ((ua >> 16) & 1u)) >> 16;
    unsigned r1 = (ub + 0x7fffu + ((ub >> 16) & 1u)) >> 16;
    return r0 | (r1 << 16);
}
__device__ inline float blo(unsigned u) { return __uint_as_float(u << 16); }
__device__ inline float bhi(unsigned u) { return __uint_as_float(u & 0xffff0000u); }

// packed 2xf32 ops (VOP3P; halves independent)
__device__ inline void pkfma(v2f& d, v2f a, v2f b) {
    asm("v_pk_fma_f32 %0, %1, %2, %0" : "+v"(d) : "v"(a), "v"(b));
}
__device__ inline void pkadd(v2f& d, v2f a) {
    asm("v_pk_add_f32 %0, %1, %0" : "+v"(d) : "v"(a));
}

// accumulate one edge's 8 bf16 dims (uint4) with UNscaled integer weight (r>>17).
// 2^-15 scale folded into epilogue (exact pow2 -> bit-identical). Zero rec -> w=0.
__device__ inline void accP(v2f& sA, v2f& sB, v2f& sC, v2f& sD, uint4 g, unsigned r) {
    float w = (float)(r >> 17);
    v2f w2 = {w, w};
    v2f e0 = {blo(g.x), bhi(g.x)};
    v2f e1 = {blo(g.y), bhi(g.y)};
    v2f e2 = {blo(g.z), bhi(g.z)};
    v2f e3 = {blo(g.w), bhi(g.w)};
    pkfma(sA, e0, w2);
    pkfma(sB, e1, w2);
    pkfma(sC, e2, w2);
    pkfma(sD, e3, w2);
}

// gather one uint4 (8 bf16 dims) of node src at dim-octet byte offset dOff.
// Cached (default) — the table is the reuse we want L2 to hold.
__device__ inline uint4 gath(const unsigned char* __restrict__ base, unsigned r, unsigned dOff) {
    unsigned off = ((r & 0x1FFFFu) << 7) + dOff;
    return *(const uint4*)(base + off);
}

// non-temporal record load: sorted[] is read-once-per-kernel — keep it OUT of L2
// so it doesn't evict gather-table lines.
__device__ inline unsigned ntl(const unsigned* __restrict__ p) {
    return __builtin_nontemporal_load(p);
}

// butterfly reduce across eg (xor 8,16,32) on a packed pair
__device__ inline void wred(v2f& s) {
    v2f t;
    t.x = __shfl_xor(s.x, 8, 64);  t.y = __shfl_xor(s.y, 8, 64);  pkadd(s, t);
    t.x = __shfl_xor(s.x, 16, 64); t.y = __shfl_xor(s.y, 16, 64); pkadd(s, t);
    t.x = __shfl_xor(s.x, 32, 64); t.y = __shfl_xor(s.y, 32, 64); pkadd(s, t);
}

// ---- shared pull body (R1-proven structure): one WAVE per dst node.
// lane = (eg=lane>>3, d8=lane&7); 32 edges in flight in the main block.
// cnt is the PADDED run length (mult of 4, pads are zero records -> w=0).
__device__ inline void pull_node(const unsigned char* __restrict__ A16,
                                 unsigned* __restrict__ B16,
                                 const unsigned* __restrict__ sorted,
                                 int node, int start, int cnt, int lane) {
    int eg = lane >> 3;
    int d8 = lane & 7;
    unsigned dOff = (unsigned)d8 << 4;
    const unsigned* ep = sorted + start;

    v2f sA = {0.f,0.f}, sB = {0.f,0.f}, sC = {0.f,0.f}, sD = {0.f,0.f};
    int j = 0;
    while (j + 32 <= cnt) {
        unsigned r0 = ntl(ep + j + eg),      r1 = ntl(ep + j + 8 + eg);
        unsigned r2 = ntl(ep + j + 16 + eg), r3 = ntl(ep + j + 24 + eg);
        uint4 g0 = gath(A16, r0, dOff);
        uint4 g1 = gath(A16, r1, dOff);
        uint4 g2 = gath(A16, r2, dOff);
        uint4 g3 = gath(A16, r3, dOff);
        accP(sA, sB, sC, sD, g0, r0);
        accP(sA, sB, sC, sD, g1, r1);
        accP(sA, sB, sC, sD, g2, r2);
        accP(sA, sB, sC, sD, g3, r3);
        j += 32;
    }
    if (j + 16 <= cnt) {
        unsigned r0 = ntl(ep + j + eg), r1 = ntl(ep + j + 8 + eg);
        uint4 g0 = gath(A16, r0, dOff);
        uint4 g1 = gath(A16, r1, dOff);
        accP(sA, sB, sC, sD, g0, r0);
        accP(sA, sB, sC, sD, g1, r1);
        j += 16;
    }
    if (j < cnt) {                       // remaining 4/8/12 (cnt mult of 4)
        int i0 = j + eg, i1 = j + 8 + eg;
        unsigned r0 = (i0 < cnt) ? ntl(ep + i0) : 0u;   // r=0 -> w=0
        unsigned r1 = (i1 < cnt) ? ntl(ep + i1) : 0u;
        uint4 g0 = gath(A16, r0, dOff);
        uint4 g1 = gath(A16, r1, dOff);
        accP(sA, sB, sC, sD, g0, r0);
        accP(sA, sB, sC, sD, g1, r1);
    }

    wred(sA); wred(sB); wred(sC); wred(sD);

    if (eg == 0) {
        const float k15 = 1.f / 32768.f;   // fold fix15 weight scale (exact pow2)
        v4u h;
        h.x = bf16pair(sA.x * k15, sA.y * k15);
        h.y = bf16pair(sB.x * k15, sB.y * k15);
        h.z = bf16pair(sC.x * k15, sC.y * k15);
        h.w = bf16pair(sD.x * k15, sD.y * k15);
        // nt store: B is not re-read within this kernel — don't evict table lines.
        v4u* dst = (v4u*)(B16 + (((long long)node) << 5) + ((long long)d8 << 2));
        __builtin_nontemporal_store(h, dst);
    }
}

// init: E0(bf16) = concat(ue, ie). Block 0 inits bucket cursors.
__global__ void init_emb_kernel(const float* __restrict__ ue,
                                const float* __restrict__ ie,
                                unsigned* __restrict__ E0,
                                int* __restrict__ bucketCursor) {
    int idx = blockIdx.x * blockDim.x + threadIdx.x;   // per float4 (4 dims)
    if (blockIdx.x == 0 && threadIdx.x < 256) {
        bucketCursor[threadIdx.x]       = threadIdx.x * CAP;
        bucketCursor[threadIdx.x + 256] = (threadIdx.x + 256) * CAP;
    }
    const int total = N_NODES * (EMB_DIM / 4);
    if (idx >= total) return;
    const int uoff = NUM_USERS * (EMB_DIM / 4);
    float4 v;
    if (idx < uoff) v = ((const float4*)ue)[idx];
    else            v = ((const float4*)ie)[idx - uoff];
    uint2 h;
    h.x = bf16pair(v.x, v.y);
    h.y = bf16pair(v.z, v.w);
    ((uint2*)E0)[idx] = h;
}

// partition edges into padded dst-bucket regions. 1024 threads, 8 edges/thread.
// rec: src(17) | dstLocal(8)<<17 | fix15(val)<<25
__global__ void partA_kernel(const float* __restrict__ ev,
                             const int*  __restrict__ es,
                             const int*  __restrict__ ed,
                             int* __restrict__ bucketCursor,
                             ull* __restrict__ tmp) {
    __shared__ int hist[NBUCK];
    __shared__ int base[NBUCK];
    __shared__ int cnt2[NBUCK];
    int tid = threadIdx.x;            // 1024
    int e0 = blockIdx.x * TILE_EDGES;

    int      mySrc[8], myDst[8];
    unsigned myQ[8];

    for (int i = tid; i < NBUCK; i += 1024) hist[i] = 0;
    __syncthreads();

    #pragma unroll
    for (int k = 0; k < 8; ++k) {
        int e = e0 + k * 1024 + tid;
        if (e < NNZ) {
            mySrc[k] = es[e];
            myDst[k] = ed[e];
            myQ[k]   = (unsigned)fminf(ev[e] * 32768.f + 0.5f, 32767.f);
            atomicAdd(&hist[((unsigned)myDst[k]) >> ABITS], 1);
        } else {
            myDst[k] = -1;
        }
    }
    __syncthreads();

    for (int i = tid; i < NBUCK; i += 1024) {
        int c = hist[i];
        base[i] = c ? atomicAdd(&bucketCursor[i], c) : 0;
        cnt2[i] = 0;
    }
    __syncthreads();

    #pragma unroll
    for (int k = 0; k < 8; ++k) {
        int dst = myDst[k];
        if (dst < 0) continue;
        int b = ((unsigned)dst) >> ABITS;
        int pos = base[b] + atomicAdd(&cnt2[b], 1);
        if (pos < (b + 1) * CAP) {   // statistically unreachable overflow guard
            ull rec = (ull)(unsigned)(mySrc[k] | ((dst & (NODES_PER_BUCK - 1)) << 17))
                    | ((ull)myQ[k] << 25);
            tmp[pos] = rec;
        }
    }
}

// partB: per bucket — 1024-cell (node x src-quarter) histogram gives each node a
// contiguous, src-quarter-SORTED record run (residual window locality), padded to
// a multiple of 4 with ZEROED pad records. deg[node] = padded run length.
// sorted rec (u32): src(17)|fix15<<17
__global__ void partB_kernel(const ull* __restrict__ tmp,
                             const int* __restrict__ bucketCursor,
                             int* __restrict__ rowStart,
                             int* __restrict__ deg,
                             unsigned* __restrict__ sorted) {
    __shared__ int cnt[NCELL];
    __shared__ int nsc[NODES_PER_BUCK];     // scan of pad4(node total)
    __shared__ int nstart[NODES_PER_BUCK];
    __shared__ int cur[NCELL];
    int b = blockIdx.x;
    int tid = threadIdx.x;           // 1024
    int nodeLo = b << ABITS;
    int startE = b * CAP;
    int endE   = bucketCursor[b];    // base + records in bucket

    cnt[tid] = 0;
    __syncthreads();

    ull myRec[9];
    int myCell[9];
    int nRec = 0;
    #pragma unroll
    for (int k = 0; k < 9; ++k) {
        int i = startE + k * 1024 + tid;
        if (i < endE) {
            myRec[k] = tmp[i];
            nRec = k + 1;
            unsigned src = (unsigned)(myRec[k] & 0x1FFFFULL);
            int q = (int)(src >> 15); if (q > 3) q = 3;
            int dl = (int)((myRec[k] >> 17) & (NODES_PER_BUCK - 1));
            myCell[k] = (dl << 2) + q;
            atomicAdd(&cnt[myCell[k]], 1);
        }
    }
    __syncthreads();

    int p4 = 0;
    if (tid < NODES_PER_BUCK) {
        int tot = cnt[tid*4] + cnt[tid*4+1] + cnt[tid*4+2] + cnt[tid*4+3];
        p4 = (tot + 3) & ~3;
        nsc[tid] = p4;
    }
    __syncthreads();
    for (int o = 1; o < NODES_PER_BUCK; o <<= 1) {
        int add = 0;
        if (tid < NODES_PER_BUCK && tid >= o) add = nsc[tid - o];
        __syncthreads();
        if (tid < NODES_PER_BUCK) nsc[tid] += add;
        __syncthreads();
    }
    if (tid < NODES_PER_BUCK) {
        int ns = startE + nsc[tid] - p4;   // 16B-aligned (startE%4==0, scan of x4)
        nstart[tid] = ns;
        int node = nodeLo + tid;
        if (node < N_NODES) {
            rowStart[node] = ns;
            deg[node] = p4;                // PADDED length; pads zeroed below
        }
    }
    __syncthreads();

    {   // exact (unpadded) cell cursors within each node's run
        int n = tid >> 2, q = tid & 3;
        int c = nstart[n];
        if (q > 0) c += cnt[n*4];
        if (q > 1) c += cnt[n*4+1];
        if (q > 2) c += cnt[n*4+2];
        cur[tid] = c;
    }
    __syncthreads();

    for (int k = 0; k < nRec; ++k) {
        ull rec = myRec[k];
        unsigned o = (unsigned)(rec & 0x1FFFFULL) | ((unsigned)((rec >> 25) & 0x7FFF) << 17);
        int pos = atomicAdd(&cur[myCell[k]], 1);
        if (pos < startE + CAP) sorted[pos] = o;  // overflow guard (stat. unreachable)
    }
    __syncthreads();

    if (tid < NODES_PER_BUCK) {        // zero the <=3 pad slots at each node tail
        int tot = cnt[tid*4] + cnt[tid*4+1] + cnt[tid*4+2] + cnt[tid*4+3];
        int end = nstart[tid] + ((tot + 3) & ~3);
        for (int p = nstart[tid] + tot; p < end; ++p)
            if (p < startE + CAP) sorted[p] = 0;
    }
}

// ---- pull_sync (ungated layers): one wave per node, R1-proven batched issue.
__global__ void pull_sync_kernel(const unsigned char* __restrict__ A16,
                                 unsigned* __restrict__ B16,
                                 const unsigned* __restrict__ sorted,
                                 const int* __restrict__ rowStart,
                                 const int* __restrict__ deg) {
    int t = blockIdx.x * blockDim.x + threadIdx.x;
    int node = __builtin_amdgcn_readfirstlane(t >> 6);
    if (node >= N_NODES) return;
    int start = rowStart[node];        // scalar (node in SGPR)
    int cnt   = deg[node];
    pull_node(A16, B16, sorted, node, start, cnt, t & 63);
}

// ---- pull_gated (layer 3): one wave per batch ENTRY (dense sweep of the 32768
// user/item indices — no flags, no dead waves). Duplicate entries store
// byte-identical rows (benign race).
__global__ void pull_gated_kernel(const unsigned char* __restrict__ A16,
                                  unsigned* __restrict__ B16,
                                  const unsigned* __restrict__ sorted,
                                  const int* __restrict__ rowStart,
                                  const int* __restrict__ deg,
                                  const int* __restrict__ users,
                                  const int* __restrict__ items) {
    int t = blockIdx.x * blockDim.x + threadIdx.x;
    int e = __builtin_amdgcn_readfirstlane(t >> 6);
    if (e >= 2 * BATCH) return;
    int node = (e < BATCH) ? users[e] : (NUM_USERS + items[e - BATCH]);
    node = __builtin_amdgcn_readfirstlane(node);
    int start = rowStart[node];
    int cnt   = deg[node];
    pull_node(A16, B16, sorted, node, start, cnt, t & 63);
}

// dot: half-wave (32 lanes) per batch element; lane covers 2 dims (one uint).
// gamma = dot( sum_l U_l , sum_l I_l ) / 16, layers read from E0,B1,B2,B3.
__global__ void dot_kernel(const unsigned* __restrict__ E0,
                           const unsigned* __restrict__ B1,
                           const unsigned* __restrict__ B2,
                           const unsigned* __restrict__ B3,
                           const int* __restrict__ users,
                           const int* __restrict__ items,
                           float* __restrict__ out) {
    int t = blockIdx.x * blockDim.x + threadIdx.x;
    int b = t >> 5;
    int lane = t & 31;
    if (b >= BATCH) return;
    long long uo = ((long long)users[b] << 5) + lane;
    long long io = ((long long)(items[b] + NUM_USERS) << 5) + lane;
    unsigned a0 = E0[uo], a1 = B1[uo], a2 = B2[uo], a3 = B3[uo];
    unsigned c0 = E0[io], c1 = B1[io], c2 = B2[io], c3 = B3[io];
    float ux = (blo(a0) + blo(a1)) + (blo(a2) + blo(a3));
    float uy = (bhi(a0) + bhi(a1)) + (bhi(a2) + bhi(a3));
    float ix = (blo(c0) + blo(c1)) + (blo(c2) + blo(c3));
    float iy = (bhi(c0) + bhi(c1)) + (bhi(c2) + bhi(c3));
    float p = ux * ix + uy * iy;
    #pragma unroll
    for (int off = 16; off >= 1; off >>= 1)
        p += __shfl_xor(p, off, 64);   // stays within the aligned 32-group
    if (lane == 0) out[b] = p * 0.0625f;
}

extern "C" void kernel_launch(void* const* d_in, const int* in_sizes, int n_in,
                              void* d_out, int out_size, void* d_ws, size_t ws_size,
                              hipStream_t stream) {
    const float* user_emb = (const float*)d_in[0];
    const float* item_emb = (const float*)d_in[1];
    const float* edge_val = (const float*)d_in[2];
    const int*   edge_src = (const int*)d_in[3];
    const int*   edge_dst = (const int*)d_in[4];
    const int*   users    = (const int*)d_in[5];
    const int*   items    = (const int*)d_in[6];
    float* out = (float*)d_out;

    const size_t emb16Bytes = (size_t)N_NODES * EMB_DIM * 2;               // 12.8 MB
    const size_t sortBytes  = (size_t)NBUCK_USED * CAP * sizeof(unsigned); // 14.8 MB
    const size_t tmpBytes   = (size_t)NBUCK_USED * CAP * sizeof(ull);      // 29.6 MB
    const size_t nodeBytes  = (size_t)N_NODES * sizeof(int);               // 400 KB

    char* w = (char*)d_ws;
    unsigned* E0           = (unsigned*)(w); w += emb16Bytes;
    unsigned* B1           = (unsigned*)(w); w += emb16Bytes;
    unsigned* B2           = (unsigned*)(w); w += emb16Bytes;
    unsigned* B3           = (unsigned*)(w); w += emb16Bytes;
    unsigned* sorted       = (unsigned*)(w); w += sortBytes;
    ull*      tmp          = (ull*)(w);      w += tmpBytes;
    int*      deg          = (int*)(w);      w += nodeBytes;
    int*      rowStart     = (int*)(w);      w += nodeBytes;
    int*      bucketCursor = (int*)(w);      w += NBUCK * sizeof(int);

    const int vecTotal   = N_NODES * (EMB_DIM / 4);
    const int initBlocks = (vecTotal + 255) / 256;
    const int tileBlocks = (NNZ + TILE_EDGES - 1) / TILE_EDGES;   // 391

    init_emb_kernel<<<initBlocks, 256, 0, stream>>>(user_emb, item_emb, E0, bucketCursor);

    partA_kernel<<<tileBlocks, 1024, 0, stream>>>(edge_val, edge_src, edge_dst,
                                                  bucketCursor, tmp);
    partB_kernel<<<NBUCK_USED, 1024, 0, stream>>>(tmp, bucketCursor,
                                                  rowStart, deg, sorted);

    const int pullBlocks = (N_NODES * 64 + 255) / 256;            // 1 node/wave
    pull_sync_kernel<<<pullBlocks, 256, 0, stream>>>((const unsigned char*)E0, B1,
                                                     sorted, rowStart, deg);
    pull_sync_kernel<<<pullBlocks, 256, 0, stream>>>((const unsigned char*)B1, B2,
                                                     sorted, rowStart, deg);

    const int gatedBlocks = (2 * BATCH * 64 + 255) / 256;         // 1 entry/wave
    pull_gated_kernel<<<gatedBlocks, 256, 0, stream>>>((const unsigned char*)B2, B3,
                                                       sorted, rowStart, deg, users, items);

    const int dotBlocks = (BATCH * 32 + 255) / 256;
    dot_kernel<<<dotBlocks, 256, 0, stream>>>(E0, B1, B2, B3, users, items, out);
}